// Round 6
// baseline (198.514 us; speedup 1.0000x reference)
//
#include <hip/hip_runtime.h>

// Problem constants: B=4, S=1024, H=1024, NH=16, DH=64, M=B*S=4096.

typedef __attribute__((ext_vector_type(8))) __bf16 bf16x8;
typedef __attribute__((ext_vector_type(4))) float f32x4;
typedef __attribute__((ext_vector_type(16))) float f32x16;
typedef __attribute__((ext_vector_type(8))) unsigned short u16x8;
typedef __attribute__((ext_vector_type(4))) unsigned short u16x4;

// workspace layout (ushort element offsets). XQ/XK/XV regions retained but unused (r15).
#define XQ_OFF 0u
#define XK_OFF 4194304u
#define XV_OFF 8388608u
#define WQ_OFF 12582912u
#define WK_OFF 13631488u
#define WV_OFF 14680064u
#define QP_OFF 15728640u
#define KP_OFF 19922944u
#define VT_OFF 24117248u   // V projection written DIRECTLY transposed: [(b*16+h)*64+dh][s]
// total = 28311552 ushorts = 54 MiB

__device__ __forceinline__ unsigned short f2bf(float f) {
  union { float f; unsigned int u; } c; c.f = f;
  return (unsigned short)((c.u + 0x7fffu + ((c.u >> 16) & 1u)) >> 16);  // RNE
}

// ---------------- fp32 -> bf16 conversion, WEIGHTS ONLY (r15) ----------------
// q/k/v conversion moved into proj_gemm's A-staging: kills 31.5MB write + re-read and
// ~2/3 of the old cvt kernel's 23us. W stays bf16-precomputed (each W elem read by 32
// blocks; convert-once still pays there).
__global__ __launch_bounds__(256) void cvtw_kernel(
    const float* __restrict__ wq, const float* __restrict__ wk, const float* __restrict__ wv,
    unsigned short* __restrict__ ws) {
  const int z = blockIdx.y;
  const float* src = z == 0 ? wq : z == 1 ? wk : wv;
  unsigned short* dst = ws + (z == 0 ? WQ_OFF : z == 1 ? WK_OFF : WV_OFF);
  const int i8 = (blockIdx.x * 256 + threadIdx.x) * 8;   // grid 512*256*8 = 1048576 exact
  const float4 f0 = *(const float4*)(src + i8);
  const float4 f1 = *(const float4*)(src + i8 + 4);
  u16x8 r;
  r[0] = f2bf(f0.x); r[1] = f2bf(f0.y); r[2] = f2bf(f0.z); r[3] = f2bf(f0.w);
  r[4] = f2bf(f1.x); r[5] = f2bf(f1.y); r[6] = f2bf(f1.z); r[7] = f2bf(f1.w);
  *(u16x8*)(dst + i8) = r;
}

// ---------------- fused projection GEMMs ----------------
// r15: A (activations) staged DIRECTLY from the fp32 inputs: per tile each thread loads
// 16 fp32 (4x dwordx4) into a named register bank (arA/arB, static indexing), converts
// (RNE casts -> v_cvt_pk_bf16_f32), and ds_write_b128's into the SAME swizzled LDS slots
// the old global_load_lds produced (source was pre-swizzled so dest is linear in tid);
// compute() unchanged. T14 split: loads issue 2 tiles ahead (1 full iter of slack covers
// L2/HBM latency), write lands after the next barrier. B keeps gload_lds. Ring of 3
// bufs, counted vmcnt(2) (= B(t),A(t+1) done; B(t+1) in flight) + lgkmcnt(0) (awrite
// visibility) before each barrier. 6-tile-period fully unrolled x5 + peeled t=30,31.
__global__ __launch_bounds__(256) void proj_gemm(
    const float* __restrict__ xq, const float* __restrict__ xk, const float* __restrict__ xv,
    unsigned short* __restrict__ ws,
    const float* __restrict__ bq, const float* __restrict__ bk, const float* __restrict__ bv) {
  __shared__ unsigned short smem[24576];  // 3 bufs x 8192 (A 4096 + B 4096); Tw overlays [0,18432)
  const int z = blockIdx.z;
  const float* XF = z == 0 ? xq : z == 1 ? xk : xv;
  const unsigned short* W = ws + (z == 0 ? WQ_OFF : z == 1 ? WK_OFF : WV_OFF);
  unsigned short* P = ws + (z == 0 ? QP_OFF : z == 1 ? KP_OFF : VT_OFF);
  const float* bias = z == 0 ? bq : z == 1 ? bk : bv;

  const int tid  = threadIdx.x;
  const int lane = tid & 63;
  const int w    = tid >> 6;
  const int l31  = lane & 31;
  const int g    = lane >> 5;
  const int wr = w >> 1, wc = w & 1;

  // XCD-aware remap: XCD j (lin%8) gets m-tiles 4j..4j+3 x all 8 n-tiles (3MB < 4MB L2).
  const int lin = blockIdx.x + 8 * blockIdx.y;   // 0..255
  const int xcd = lin & 7;
  const int idx = lin >> 3;                      // 0..31
  const int m0 = (xcd * 4 + (idx >> 3)) * 128;
  const int n0 = (idx & 7) * 128;

  f32x16 acc[2][2];
#pragma unroll
  for (int i = 0; i < 2; ++i)
#pragma unroll
    for (int j = 0; j < 2; ++j)
#pragma unroll
      for (int r = 0; r < 16; ++r) acc[i][j][r] = 0.f;

  const int c1 = 256 + tid;
  const int row0 = tid >> 2, kc0 = (((tid & 3) ^ ((row0 >> 1) & 3)) * 8);
  const int row1 = c1 >> 2,  kc1 = (((c1 & 3) ^ ((row1 >> 1) & 3)) * 8);
  const float* gAf0 = XF + (size_t)(m0 + row0) * 1024 + kc0;   // fp32 A source, pre-swizzled
  const float* gAf1 = XF + (size_t)(m0 + row1) * 1024 + kc1;
  const unsigned short* gB0 = W + (size_t)(n0 + row0) * 1024 + kc0;
  const unsigned short* gB1 = W + (size_t)(n0 + row1) * 1024 + kc1;
  const int d0 = w * 512, d1 = 2048 + w * 512;

  f32x4 arA[4], arB[4];   // two named A-register banks (static indexing, rule #20)

  auto aload = [&](f32x4 (&bank)[4]) {
    bank[0] = *(const f32x4*)gAf0; bank[1] = *(const f32x4*)(gAf0 + 4);
    bank[2] = *(const f32x4*)gAf1; bank[3] = *(const f32x4*)(gAf1 + 4);
    gAf0 += 32; gAf1 += 32;
  };
  auto issueB = [&](int buf) {
    unsigned short* Bb = smem + buf * 8192 + 4096;
    __builtin_amdgcn_global_load_lds((const __attribute__((address_space(1))) void*)gB0,
                                     (__attribute__((address_space(3))) void*)(Bb + d0), 16, 0, 0);
    __builtin_amdgcn_global_load_lds((const __attribute__((address_space(1))) void*)gB1,
                                     (__attribute__((address_space(3))) void*)(Bb + d1), 16, 0, 0);
    gB0 += 32; gB1 += 32;
  };
  auto awrite = [&](int buf, const f32x4 (&bank)[4]) {
    unsigned short* Ab = smem + buf * 8192;
    bf16x8 w0, w1;
    w0[0] = (__bf16)bank[0][0]; w0[1] = (__bf16)bank[0][1];
    w0[2] = (__bf16)bank[0][2]; w0[3] = (__bf16)bank[0][3];
    w0[4] = (__bf16)bank[1][0]; w0[5] = (__bf16)bank[1][1];
    w0[6] = (__bf16)bank[1][2]; w0[7] = (__bf16)bank[1][3];
    w1[0] = (__bf16)bank[2][0]; w1[1] = (__bf16)bank[2][1];
    w1[2] = (__bf16)bank[2][2]; w1[3] = (__bf16)bank[2][3];
    w1[4] = (__bf16)bank[3][0]; w1[5] = (__bf16)bank[3][1];
    w1[6] = (__bf16)bank[3][2]; w1[7] = (__bf16)bank[3][3];
    *(bf16x8*)&Ab[tid * 8] = w0;          // byte 16*tid: linear dest (src pre-swizzled)
    *(bf16x8*)&Ab[2048 + tid * 8] = w1;
  };
  auto compute = [&](int buf) {
    const unsigned short* Ab = smem + buf * 8192;
    const unsigned short* Bb = Ab + 4096;
    bf16x8 af[2][2], bfv[2][2];
#pragma unroll
    for (int mt = 0; mt < 2; ++mt)
#pragma unroll
      for (int kk = 0; kk < 2; ++kk) {
        const int ra = wr * 64 + mt * 32 + l31;
        af[mt][kk] = *(const bf16x8*)&Ab[ra * 32 + (((kk * 2 + g) ^ ((ra >> 1) & 3)) * 8)];
      }
#pragma unroll
    for (int nt = 0; nt < 2; ++nt)
#pragma unroll
      for (int kk = 0; kk < 2; ++kk) {
        const int rb = wc * 64 + nt * 32 + l31;
        bfv[nt][kk] = *(const bf16x8*)&Bb[rb * 32 + (((kk * 2 + g) ^ ((rb >> 1) & 3)) * 8)];
      }
    __builtin_amdgcn_s_setprio(1);
#pragma unroll
    for (int mt = 0; mt < 2; ++mt)
#pragma unroll
      for (int nt = 0; nt < 2; ++nt)
#pragma unroll
        for (int kk = 0; kk < 2; ++kk)
          acc[mt][nt] = __builtin_amdgcn_mfma_f32_32x32x16_bf16(af[mt][kk], bfv[nt][kk],
                                                                acc[mt][nt], 0, 0, 0);
    __builtin_amdgcn_s_setprio(0);
  };

  // body for tile t: compute buf t%3; awrite tile t+1 (bank (t+1)&1) into buf (t+1)%3;
  // aload tile t+2 into bank (t+2)&1; issueB tile t+2 into buf (t+2)%3.
  auto body = [&](int bufC, int bufW, int bufB, const f32x4 (&bw)[4], f32x4 (&bl)[4]) {
    asm volatile("s_waitcnt vmcnt(2) lgkmcnt(0)" ::: "memory");  // B(t),A(t+1) done; awrite(t) visible
    __builtin_amdgcn_s_barrier();
    awrite(bufW, bw);
    aload(bl);
    issueB(bufB);
    compute(bufC);
  };

  // prologue: tiles 0,1 in flight
  aload(arA);        // A0
  issueB(0);         // B0
  aload(arB);        // A1
  issueB(1);         // B1                queue: [A0 4, B0 2, A1 4, B1 2]
  asm volatile("s_waitcnt vmcnt(8)" ::: "memory");   // A0 done
  awrite(0, arA);

  // main: tiles 0..29, period-6 static pattern
  for (int it = 0; it < 5; ++it) {
    body(0, 1, 2, arB, arA);   // t%6==0
    body(1, 2, 0, arA, arB);   // t%6==1
    body(2, 0, 1, arB, arA);   // t%6==2
    body(0, 1, 2, arA, arB);   // t%6==3
    body(1, 2, 0, arB, arA);   // t%6==4
    body(2, 0, 1, arA, arB);   // t%6==5
  }
  // t=30: queue [B30 2, A31 4, B31 2]
  asm volatile("s_waitcnt vmcnt(2) lgkmcnt(0)" ::: "memory");
  __builtin_amdgcn_s_barrier();
  awrite(1, arB);              // tile 31 -> buf 1
  compute(0);                  // tile 30
  // t=31
  asm volatile("s_waitcnt vmcnt(0) lgkmcnt(0)" ::: "memory");
  __builtin_amdgcn_s_barrier();
  compute(1);                  // tile 31

  // Tw overlay [0,18432) overlaps all bufs: drain LDS reads, then barrier.
  asm volatile("s_waitcnt lgkmcnt(0)" ::: "memory");
  __builtin_amdgcn_s_barrier();

  unsigned short* Tw = smem + w * 4608;  // 64 * 72
  if (z != 2) {
#pragma unroll
    for (int mt = 0; mt < 2; ++mt)
#pragma unroll
      for (int nt = 0; nt < 2; ++nt) {
        const float bvv = bias[n0 + wc * 64 + nt * 32 + l31];
#pragma unroll
        for (int reg = 0; reg < 16; ++reg) {
          const int rloc = (reg & 3) + 8 * (reg >> 2) + 4 * g;
          float v = acc[mt][nt][reg] + bvv;
          v = v > 0.f ? v : 0.f;
          Tw[(mt * 32 + rloc) * 72 + nt * 32 + l31] = f2bf(v);
        }
      }
    const int row0g = m0 + wr * 64;
    const int colb  = n0 + wc * 64;
#pragma unroll
    for (int i = 0; i < 8; ++i) {
      const int rr = i * 8 + (lane >> 3);
      const int cc = (lane & 7) * 8;
      *(u16x8*)&P[(size_t)(row0g + rr) * 1024 + colb + cc] = *(const u16x8*)&Tw[rr * 72 + cc];
    }
  } else {
#pragma unroll
    for (int mt = 0; mt < 2; ++mt)
#pragma unroll
      for (int nt = 0; nt < 2; ++nt) {
        const float bvv = bias[n0 + wc * 64 + nt * 32 + l31];
#pragma unroll
        for (int rq = 0; rq < 4; ++rq) {
          u16x4 pk;
#pragma unroll
          for (int r = 0; r < 4; ++r) {
            float v = acc[mt][nt][rq * 4 + r] + bvv;
            v = v > 0.f ? v : 0.f;
            pk[r] = f2bf(v);
          }
          *(u16x4*)&Tw[(nt * 32 + l31) * 72 + mt * 32 + rq * 8 + g * 4] = pk;
        }
      }
    const int h2 = (n0 >> 6) + wc;
    const int bb = m0 >> 10;
    const int s0 = (m0 & 1023) + wr * 64;
#pragma unroll
    for (int i = 0; i < 8; ++i) {
      const int rr = i * 8 + (lane >> 3);
      const int cc = (lane & 7) * 8;
      *(u16x8*)&P[((size_t)(bb * 16 + h2) * 64 + rr) * 1024 + s0 + cc] =
          *(const u16x8*)&Tw[rr * 72 + cc];
    }
  }
}

// ---------------- fused flash attention + mask + residual ----------------
// r13 (passing, ~31us): 3-buffer K/V ring, prefetch distance 2, counted vmcnt(4) +
// raw s_barrier; __builtin_amdgcn_exp2f softmax; s_setprio around MFMA clusters;
// lacc=mfma(pa,ones) denominator. Unchanged this round.
__global__ __launch_bounds__(256, 2) void attn_kernel(
    const unsigned short* __restrict__ QP, const unsigned short* __restrict__ KP,
    const unsigned short* __restrict__ VT, const float* __restrict__ masks,
    const float* __restrict__ query, float* __restrict__ out) {
  __shared__ unsigned short Kt[3][64 * 64];  // [key][dh], chunk-swizzled, no pad (DMA dest)
  __shared__ unsigned short Vt[3][64 * 64];  // [dh][key], chunk-swizzled, no pad (DMA dest)
  __shared__ unsigned short Pl[4][32 * 72];  // per-wave P [q][key], padded (wave-private)
  const int tid  = threadIdx.x;
  const int lane = tid & 63;
  const int w    = tid >> 6;
  const int quad = lane >> 4;
  const int l15  = lane & 15;
  const int bh = blockIdx.x;                 // b*16 + h
  const int b = bh >> 4, h = bh & 15;
  const int q0w = blockIdx.y * 128 + w * 32;
  const size_t base = (size_t)b * 1024 * 1024;

  bf16x8 qf[2][2];
#pragma unroll
  for (int mt = 0; mt < 2; ++mt)
#pragma unroll
    for (int kk = 0; kk < 2; ++kk)
      qf[mt][kk] = *(const bf16x8*)&QP[base + (size_t)(q0w + mt * 16 + l15) * 1024 +
                                       h * 64 + kk * 32 + quad * 8];

  f32x4 o[2][4];
  f32x4 lacc[2];
#pragma unroll
  for (int mt = 0; mt < 2; ++mt) {
    lacc[mt] = f32x4{0.f, 0.f, 0.f, 0.f};
#pragma unroll
    for (int nd = 0; nd < 4; ++nd) o[mt][nd] = f32x4{0.f, 0.f, 0.f, 0.f};
  }

  bf16x8 onesb;
#pragma unroll
  for (int i = 0; i < 8; ++i) onesb[i] = (__bf16)1.0f;

  const int r_st = lane >> 3;
  const int pc   = lane & 7;
  const int swz  = l15 & 7;
  const float cvt = 0.18033688011112042f;  // (1/sqrt(64)) * log2(e)

  auto stage = [&](int key0, int buf) {
#pragma unroll
    for (int t = 0; t < 2; ++t) {
      const int rowk = (w * 2 + t) * 8 + r_st;
      const int lc   = pc ^ (rowk & 7);
      const unsigned short* gk = &KP[base + (size_t)(key0 + rowk) * 1024 + h * 64 + lc * 8];
      const unsigned short* gv = &VT[((size_t)bh * 64 + rowk) * 1024 + key0 + lc * 8];
      __builtin_amdgcn_global_load_lds((const __attribute__((address_space(1))) void*)gk,
                                       (__attribute__((address_space(3))) void*)&Kt[buf][(w * 2 + t) * 512],
                                       16, 0, 0);
      __builtin_amdgcn_global_load_lds((const __attribute__((address_space(1))) void*)gv,
                                       (__attribute__((address_space(3))) void*)&Vt[buf][(w * 2 + t) * 512],
                                       16, 0, 0);
    }
  };

  auto step = [&](int buf) {
    const unsigned short* Ktb = Kt[buf];
    const unsigned short* Vtb = Vt[buf];

    bf16x8 kf[2][4];
#pragma unroll
    for (int kk = 0; kk < 2; ++kk)
#pragma unroll
      for (int ni = 0; ni < 4; ++ni)
        kf[kk][ni] = *(const bf16x8*)&Ktb[(ni * 16 + l15) * 64 + ((kk * 4 + quad) ^ swz) * 8];

    // S^T = K.Q^T per m-subtile; C-layout: row=key=quad*4+reg(+16ni), col=q=l15
#pragma unroll
    for (int mt = 0; mt < 2; ++mt) {
      f32x4 st[4];
#pragma unroll
      for (int ni = 0; ni < 4; ++ni) st[ni] = f32x4{0.f, 0.f, 0.f, 0.f};
      __builtin_amdgcn_s_setprio(1);
#pragma unroll
      for (int kk = 0; kk < 2; ++kk)
#pragma unroll
        for (int ni = 0; ni < 4; ++ni)
          st[ni] = __builtin_amdgcn_mfma_f32_16x16x32_bf16(kf[kk][ni], qf[mt][kk], st[ni], 0, 0, 0);
      __builtin_amdgcn_s_setprio(0);
#pragma unroll
      for (int ni = 0; ni < 4; ++ni) {
        float p0 = __builtin_amdgcn_exp2f(fmaf(st[ni][0], cvt, -8.0f));  // fixed shift, exact
        float p1 = __builtin_amdgcn_exp2f(fmaf(st[ni][1], cvt, -8.0f));
        float p2 = __builtin_amdgcn_exp2f(fmaf(st[ni][2], cvt, -8.0f));
        float p3 = __builtin_amdgcn_exp2f(fmaf(st[ni][3], cvt, -8.0f));
        const unsigned int u0 = __float_as_uint(p0) + 0x8000u;  // round-half-up to bf16
        const unsigned int u1 = __float_as_uint(p1) + 0x8000u;
        const unsigned int u2 = __float_as_uint(p2) + 0x8000u;
        const unsigned int u3 = __float_as_uint(p3) + 0x8000u;
        uint2 pk;
        pk.x = (u0 >> 16) | (u1 & 0xffff0000u);  // folds to v_perm_b32
        pk.y = (u2 >> 16) | (u3 & 0xffff0000u);
        *(uint2*)&Pl[w][(mt * 16 + l15) * 72 + ni * 16 + quad * 4] = pk;
      }
    }

    // O += P.V (and lacc += P.ones for the softmax denominator)
#pragma unroll
    for (int kk = 0; kk < 2; ++kk) {
      bf16x8 pa[2];
#pragma unroll
      for (int mt = 0; mt < 2; ++mt)
        pa[mt] = *(const bf16x8*)&Pl[w][(mt * 16 + l15) * 72 + kk * 32 + quad * 8];
      __builtin_amdgcn_s_setprio(1);
#pragma unroll
      for (int mt = 0; mt < 2; ++mt)
        lacc[mt] = __builtin_amdgcn_mfma_f32_16x16x32_bf16(pa[mt], onesb, lacc[mt], 0, 0, 0);
#pragma unroll
      for (int nd = 0; nd < 4; ++nd) {
        bf16x8 vf = *(const bf16x8*)&Vtb[(nd * 16 + l15) * 64 + ((kk * 4 + quad) ^ swz) * 8];
#pragma unroll
        for (int mt = 0; mt < 2; ++mt)
          o[mt][nd] = __builtin_amdgcn_mfma_f32_16x16x32_bf16(pa[mt], vf, o[mt][nd], 0, 0, 0);
      }
      __builtin_amdgcn_s_setprio(0);
    }
  };

  // pipeline: tiles 0..15, tile t in buf t%3, prefetch distance 2.
  // per-wave stage = 4 gload_lds -> vmcnt(4): tile kb landed, tile kb+1 in flight.
  stage(0, 0);
  stage(64, 1);
  for (int kb = 0; kb < 15; ++kb) {
    asm volatile("s_waitcnt vmcnt(4)" ::: "memory");
    __builtin_amdgcn_s_barrier();
    if (kb < 14) stage((kb + 2) * 64, (kb + 2) % 3);  // overwrites buf (kb-1)%3: read done pre-barrier
    step(kb % 3);
  }
  asm volatile("s_waitcnt vmcnt(0)" ::: "memory");
  __builtin_amdgcn_s_barrier();
  step(0);                                             // tile 15 (15%3==0)

  // epilogue: out = mask[q] * O / l + query ; lacc[mt][r] = full row sum (all cols equal)
#pragma unroll
  for (int mt = 0; mt < 2; ++mt)
#pragma unroll
    for (int r = 0; r < 4; ++r) {
      const int rq = quad * 4 + r;
      const int row = q0w + mt * 16 + rq;
      const float scale = masks[b * 1024 + row] / lacc[mt][r];
#pragma unroll
      for (int nd = 0; nd < 4; ++nd) {
        const int col = h * 64 + nd * 16 + l15;
        const size_t gi = base + (size_t)row * 1024 + col;
        out[gi] = o[mt][nd][r] * scale + query[gi];
      }
    }
}

extern "C" void kernel_launch(void* const* d_in, const int* in_sizes, int n_in,
                              void* d_out, int out_size, void* d_ws, size_t ws_size,
                              hipStream_t stream) {
  const float* q     = (const float*)d_in[0];
  const float* k     = (const float*)d_in[1];
  const float* v     = (const float*)d_in[2];
  const float* masks = (const float*)d_in[3];
  const float* Wq    = (const float*)d_in[4];
  const float* bq    = (const float*)d_in[5];
  const float* Wk    = (const float*)d_in[6];
  const float* bk    = (const float*)d_in[7];
  const float* Wv    = (const float*)d_in[8];
  const float* bv    = (const float*)d_in[9];
  float* out = (float*)d_out;
  unsigned short* ws = (unsigned short*)d_ws;

  cvtw_kernel<<<dim3(512, 3), 256, 0, stream>>>(Wq, Wk, Wv, ws);
  proj_gemm<<<dim3(8, 32, 3), 256, 0, stream>>>(q, k, v, ws, bq, bk, bv);
  attn_kernel<<<dim3(64, 8), 256, 0, stream>>>(ws + QP_OFF, ws + KP_OFF, ws + VT_OFF,
                                               masks, q, out);
}

// Round 7
// 171.736 us; speedup vs baseline: 1.1559x; 1.1559x over previous
//
#include <hip/hip_runtime.h>

// Problem constants: B=4, S=1024, H=1024, NH=16, DH=64, M=B*S=4096.

typedef __attribute__((ext_vector_type(8))) __bf16 bf16x8;
typedef __attribute__((ext_vector_type(4))) float f32x4;
typedef __attribute__((ext_vector_type(16))) float f32x16;
typedef __attribute__((ext_vector_type(8))) unsigned short u16x8;
typedef __attribute__((ext_vector_type(4))) unsigned short u16x4;

// workspace layout (ushort element offsets)
#define XQ_OFF 0u
#define XK_OFF 4194304u
#define XV_OFF 8388608u
#define WQ_OFF 12582912u
#define WK_OFF 13631488u
#define WV_OFF 14680064u
#define QP_OFF 15728640u
#define KP_OFF 19922944u
#define VT_OFF 24117248u   // V projection written DIRECTLY transposed: [(b*16+h)*64+dh][s]
// total = 28311552 ushorts = 54 MiB

__device__ __forceinline__ unsigned short f2bf(float f) {
  union { float f; unsigned int u; } c; c.f = f;
  return (unsigned short)((c.u + 0x7fffu + ((c.u >> 16) & 1u)) >> 16);  // RNE
}

// ---------------- fp32 -> bf16 conversion of inputs ----------------
// r16: restored (r15's fused-A-conversion regressed proj 40->80us; T14 reg-staging is
// net-negative vs global_load_lds on GEMM — guide m151/m249 lesson, now confirmed here).
__global__ __launch_bounds__(256) void cvt_kernel(
    const float* __restrict__ q, const float* __restrict__ k, const float* __restrict__ v,
    const float* __restrict__ wq, const float* __restrict__ wk, const float* __restrict__ wv,
    unsigned short* __restrict__ ws) {
  const int z = blockIdx.y;
  const float* src; unsigned short* dst; int n;
  switch (z) {
    case 0: src = q;  dst = ws + XQ_OFF; n = 4194304; break;
    case 1: src = k;  dst = ws + XK_OFF; n = 4194304; break;
    case 2: src = v;  dst = ws + XV_OFF; n = 4194304; break;
    case 3: src = wq; dst = ws + WQ_OFF; n = 1048576; break;
    case 4: src = wk; dst = ws + WK_OFF; n = 1048576; break;
    default: src = wv; dst = ws + WV_OFF; n = 1048576; break;
  }
  const int i8 = (blockIdx.x * 256 + threadIdx.x) * 8;
  if (i8 >= n) return;
  const float4 f0 = *(const float4*)(src + i8);
  const float4 f1 = *(const float4*)(src + i8 + 4);
  u16x8 r;
  r[0] = f2bf(f0.x); r[1] = f2bf(f0.y); r[2] = f2bf(f0.z); r[3] = f2bf(f0.w);
  r[4] = f2bf(f1.x); r[5] = f2bf(f1.y); r[6] = f2bf(f1.z); r[7] = f2bf(f1.w);
  *(u16x8*)(dst + i8) = r;
}

// ---------------- fused projection GEMMs ----------------
// r16 == r14 minus the compute-cluster s_setprio (m190: setprio is null-to-negative on
// lockstep barrier-synced GEMM; it only pays on phase-split schedules). Structure: 3-buf
// gload_lds ring (48KB -> 3 WG/CU), prefetch distance 2, counted vmcnt(4) steady state,
// vmcnt(0) last tile only, one lgkmcnt(0)+barrier before the Tw epilogue overlay.
__global__ __launch_bounds__(256) void proj_gemm(
    unsigned short* __restrict__ ws,
    const float* __restrict__ bq, const float* __restrict__ bk, const float* __restrict__ bv) {
  __shared__ unsigned short smem[24576];  // 3 bufs x 8192 (A 4096 + B 4096); Tw overlays [0,18432)
  const int z = blockIdx.z;
  const unsigned short* X = ws + (z == 0 ? XQ_OFF : z == 1 ? XK_OFF : XV_OFF);
  const unsigned short* W = ws + (z == 0 ? WQ_OFF : z == 1 ? WK_OFF : WV_OFF);
  unsigned short* P = ws + (z == 0 ? QP_OFF : z == 1 ? KP_OFF : VT_OFF);
  const float* bias = z == 0 ? bq : z == 1 ? bk : bv;

  const int tid  = threadIdx.x;
  const int lane = tid & 63;
  const int w    = tid >> 6;
  const int l31  = lane & 31;
  const int g    = lane >> 5;
  const int wr = w >> 1, wc = w & 1;

  // XCD-aware remap: XCD j (lin%8) gets m-tiles 4j..4j+3 x all 8 n-tiles (3MB < 4MB L2).
  const int lin = blockIdx.x + 8 * blockIdx.y;   // 0..255
  const int xcd = lin & 7;
  const int idx = lin >> 3;                      // 0..31
  const int m0 = (xcd * 4 + (idx >> 3)) * 128;
  const int n0 = (idx & 7) * 128;

  f32x16 acc[2][2];
#pragma unroll
  for (int i = 0; i < 2; ++i)
#pragma unroll
    for (int j = 0; j < 2; ++j)
#pragma unroll
      for (int r = 0; r < 16; ++r) acc[i][j][r] = 0.f;

  const int c1 = 256 + tid;
  const int row0 = tid >> 2, kc0 = (((tid & 3) ^ ((row0 >> 1) & 3)) * 8);
  const int row1 = c1 >> 2,  kc1 = (((c1 & 3) ^ ((row1 >> 1) & 3)) * 8);
  const unsigned short* gA0 = X + (size_t)(m0 + row0) * 1024 + kc0;
  const unsigned short* gA1 = X + (size_t)(m0 + row1) * 1024 + kc1;
  const unsigned short* gB0 = W + (size_t)(n0 + row0) * 1024 + kc0;
  const unsigned short* gB1 = W + (size_t)(n0 + row1) * 1024 + kc1;
  const int d0 = w * 512, d1 = 2048 + w * 512;

  auto stage = [&](int buf) {
    unsigned short* Ab = smem + buf * 8192;
    unsigned short* Bb = Ab + 4096;
    __builtin_amdgcn_global_load_lds((const __attribute__((address_space(1))) void*)gA0,
                                     (__attribute__((address_space(3))) void*)(Ab + d0), 16, 0, 0);
    __builtin_amdgcn_global_load_lds((const __attribute__((address_space(1))) void*)gB0,
                                     (__attribute__((address_space(3))) void*)(Bb + d0), 16, 0, 0);
    __builtin_amdgcn_global_load_lds((const __attribute__((address_space(1))) void*)gA1,
                                     (__attribute__((address_space(3))) void*)(Ab + d1), 16, 0, 0);
    __builtin_amdgcn_global_load_lds((const __attribute__((address_space(1))) void*)gB1,
                                     (__attribute__((address_space(3))) void*)(Bb + d1), 16, 0, 0);
    gA0 += 32; gA1 += 32; gB0 += 32; gB1 += 32;
  };
  auto compute = [&](int buf) {
    const unsigned short* Ab = smem + buf * 8192;
    const unsigned short* Bb = Ab + 4096;
    bf16x8 af[2][2], bfv[2][2];
#pragma unroll
    for (int mt = 0; mt < 2; ++mt)
#pragma unroll
      for (int kk = 0; kk < 2; ++kk) {
        const int ra = wr * 64 + mt * 32 + l31;
        af[mt][kk] = *(const bf16x8*)&Ab[ra * 32 + (((kk * 2 + g) ^ ((ra >> 1) & 3)) * 8)];
      }
#pragma unroll
    for (int nt = 0; nt < 2; ++nt)
#pragma unroll
      for (int kk = 0; kk < 2; ++kk) {
        const int rb = wc * 64 + nt * 32 + l31;
        bfv[nt][kk] = *(const bf16x8*)&Bb[rb * 32 + (((kk * 2 + g) ^ ((rb >> 1) & 3)) * 8)];
      }
#pragma unroll
    for (int mt = 0; mt < 2; ++mt)
#pragma unroll
      for (int nt = 0; nt < 2; ++nt)
#pragma unroll
        for (int kk = 0; kk < 2; ++kk)
          acc[mt][nt] = __builtin_amdgcn_mfma_f32_32x32x16_bf16(af[mt][kk], bfv[nt][kk],
                                                                acc[mt][nt], 0, 0, 0);
  };

  // pipeline: tiles 0..31, tile t lives in buf t%3, prefetch distance 2.
  // steady-state wait: outstanding = tiles t,t+1 (8 loads) -> vmcnt(4) = tile t landed.
  stage(0); stage(1);
  for (int t = 0; t < 31; ++t) {
    asm volatile("s_waitcnt vmcnt(4)" ::: "memory");
    __builtin_amdgcn_s_barrier();                      // all waves' portions visible
    if (t < 30) stage((t + 2) % 3);                    // buf (t-1)%3: read done pre-barrier
    compute(t % 3);
  }
  asm volatile("s_waitcnt vmcnt(0)" ::: "memory");
  __builtin_amdgcn_s_barrier();
  compute(31 % 3);                                     // tile 31 in buf 1

  // buf 1 [8192,16384) overlaps Tw [0,18432): wait own LDS reads, then barrier.
  asm volatile("s_waitcnt lgkmcnt(0)" ::: "memory");
  __builtin_amdgcn_s_barrier();

  unsigned short* Tw = smem + w * 4608;  // 64 * 72
  if (z != 2) {
#pragma unroll
    for (int mt = 0; mt < 2; ++mt)
#pragma unroll
      for (int nt = 0; nt < 2; ++nt) {
        const float bvv = bias[n0 + wc * 64 + nt * 32 + l31];
#pragma unroll
        for (int reg = 0; reg < 16; ++reg) {
          const int rloc = (reg & 3) + 8 * (reg >> 2) + 4 * g;
          float v = acc[mt][nt][reg] + bvv;
          v = v > 0.f ? v : 0.f;
          Tw[(mt * 32 + rloc) * 72 + nt * 32 + l31] = f2bf(v);
        }
      }
    const int row0g = m0 + wr * 64;
    const int colb  = n0 + wc * 64;
#pragma unroll
    for (int i = 0; i < 8; ++i) {
      const int rr = i * 8 + (lane >> 3);
      const int cc = (lane & 7) * 8;
      *(u16x8*)&P[(size_t)(row0g + rr) * 1024 + colb + cc] = *(const u16x8*)&Tw[rr * 72 + cc];
    }
  } else {
#pragma unroll
    for (int mt = 0; mt < 2; ++mt)
#pragma unroll
      for (int nt = 0; nt < 2; ++nt) {
        const float bvv = bias[n0 + wc * 64 + nt * 32 + l31];
#pragma unroll
        for (int rq = 0; rq < 4; ++rq) {
          u16x4 pk;
#pragma unroll
          for (int r = 0; r < 4; ++r) {
            float v = acc[mt][nt][rq * 4 + r] + bvv;
            v = v > 0.f ? v : 0.f;
            pk[r] = f2bf(v);
          }
          *(u16x4*)&Tw[(nt * 32 + l31) * 72 + mt * 32 + rq * 8 + g * 4] = pk;
        }
      }
    const int h2 = (n0 >> 6) + wc;
    const int bb = m0 >> 10;
    const int s0 = (m0 & 1023) + wr * 64;
#pragma unroll
    for (int i = 0; i < 8; ++i) {
      const int rr = i * 8 + (lane >> 3);
      const int cc = (lane & 7) * 8;
      *(u16x8*)&P[((size_t)(bb * 16 + h2) * 64 + rr) * 1024 + s0 + cc] =
          *(const u16x8*)&Tw[rr * 72 + cc];
    }
  }
}

// ---------------- fused flash attention + mask + residual ----------------
// r13 (passing, ~31-35us): 3-buffer K/V ring, prefetch distance 2, counted vmcnt(4) +
// raw s_barrier; __builtin_amdgcn_exp2f softmax; s_setprio around MFMA clusters (m191:
// +4-7% on attn); lacc=mfma(pa,ones) denominator. Unchanged.
__global__ __launch_bounds__(256, 2) void attn_kernel(
    const unsigned short* __restrict__ QP, const unsigned short* __restrict__ KP,
    const unsigned short* __restrict__ VT, const float* __restrict__ masks,
    const float* __restrict__ query, float* __restrict__ out) {
  __shared__ unsigned short Kt[3][64 * 64];  // [key][dh], chunk-swizzled, no pad (DMA dest)
  __shared__ unsigned short Vt[3][64 * 64];  // [dh][key], chunk-swizzled, no pad (DMA dest)
  __shared__ unsigned short Pl[4][32 * 72];  // per-wave P [q][key], padded (wave-private)
  const int tid  = threadIdx.x;
  const int lane = tid & 63;
  const int w    = tid >> 6;
  const int quad = lane >> 4;
  const int l15  = lane & 15;
  const int bh = blockIdx.x;                 // b*16 + h
  const int b = bh >> 4, h = bh & 15;
  const int q0w = blockIdx.y * 128 + w * 32;
  const size_t base = (size_t)b * 1024 * 1024;

  bf16x8 qf[2][2];
#pragma unroll
  for (int mt = 0; mt < 2; ++mt)
#pragma unroll
    for (int kk = 0; kk < 2; ++kk)
      qf[mt][kk] = *(const bf16x8*)&QP[base + (size_t)(q0w + mt * 16 + l15) * 1024 +
                                       h * 64 + kk * 32 + quad * 8];

  f32x4 o[2][4];
  f32x4 lacc[2];
#pragma unroll
  for (int mt = 0; mt < 2; ++mt) {
    lacc[mt] = f32x4{0.f, 0.f, 0.f, 0.f};
#pragma unroll
    for (int nd = 0; nd < 4; ++nd) o[mt][nd] = f32x4{0.f, 0.f, 0.f, 0.f};
  }

  bf16x8 onesb;
#pragma unroll
  for (int i = 0; i < 8; ++i) onesb[i] = (__bf16)1.0f;

  const int r_st = lane >> 3;
  const int pc   = lane & 7;
  const int swz  = l15 & 7;
  const float cvt = 0.18033688011112042f;  // (1/sqrt(64)) * log2(e)

  auto stage = [&](int key0, int buf) {
#pragma unroll
    for (int t = 0; t < 2; ++t) {
      const int rowk = (w * 2 + t) * 8 + r_st;
      const int lc   = pc ^ (rowk & 7);
      const unsigned short* gk = &KP[base + (size_t)(key0 + rowk) * 1024 + h * 64 + lc * 8];
      const unsigned short* gv = &VT[((size_t)bh * 64 + rowk) * 1024 + key0 + lc * 8];
      __builtin_amdgcn_global_load_lds((const __attribute__((address_space(1))) void*)gk,
                                       (__attribute__((address_space(3))) void*)&Kt[buf][(w * 2 + t) * 512],
                                       16, 0, 0);
      __builtin_amdgcn_global_load_lds((const __attribute__((address_space(1))) void*)gv,
                                       (__attribute__((address_space(3))) void*)&Vt[buf][(w * 2 + t) * 512],
                                       16, 0, 0);
    }
  };

  auto step = [&](int buf) {
    const unsigned short* Ktb = Kt[buf];
    const unsigned short* Vtb = Vt[buf];

    bf16x8 kf[2][4];
#pragma unroll
    for (int kk = 0; kk < 2; ++kk)
#pragma unroll
      for (int ni = 0; ni < 4; ++ni)
        kf[kk][ni] = *(const bf16x8*)&Ktb[(ni * 16 + l15) * 64 + ((kk * 4 + quad) ^ swz) * 8];

    // S^T = K.Q^T per m-subtile; C-layout: row=key=quad*4+reg(+16ni), col=q=l15
#pragma unroll
    for (int mt = 0; mt < 2; ++mt) {
      f32x4 st[4];
#pragma unroll
      for (int ni = 0; ni < 4; ++ni) st[ni] = f32x4{0.f, 0.f, 0.f, 0.f};
      __builtin_amdgcn_s_setprio(1);
#pragma unroll
      for (int kk = 0; kk < 2; ++kk)
#pragma unroll
        for (int ni = 0; ni < 4; ++ni)
          st[ni] = __builtin_amdgcn_mfma_f32_16x16x32_bf16(kf[kk][ni], qf[mt][kk], st[ni], 0, 0, 0);
      __builtin_amdgcn_s_setprio(0);
#pragma unroll
      for (int ni = 0; ni < 4; ++ni) {
        float p0 = __builtin_amdgcn_exp2f(fmaf(st[ni][0], cvt, -8.0f));  // fixed shift, exact
        float p1 = __builtin_amdgcn_exp2f(fmaf(st[ni][1], cvt, -8.0f));
        float p2 = __builtin_amdgcn_exp2f(fmaf(st[ni][2], cvt, -8.0f));
        float p3 = __builtin_amdgcn_exp2f(fmaf(st[ni][3], cvt, -8.0f));
        const unsigned int u0 = __float_as_uint(p0) + 0x8000u;  // round-half-up to bf16
        const unsigned int u1 = __float_as_uint(p1) + 0x8000u;
        const unsigned int u2 = __float_as_uint(p2) + 0x8000u;
        const unsigned int u3 = __float_as_uint(p3) + 0x8000u;
        uint2 pk;
        pk.x = (u0 >> 16) | (u1 & 0xffff0000u);  // folds to v_perm_b32
        pk.y = (u2 >> 16) | (u3 & 0xffff0000u);
        *(uint2*)&Pl[w][(mt * 16 + l15) * 72 + ni * 16 + quad * 4] = pk;
      }
    }

    // O += P.V (and lacc += P.ones for the softmax denominator)
#pragma unroll
    for (int kk = 0; kk < 2; ++kk) {
      bf16x8 pa[2];
#pragma unroll
      for (int mt = 0; mt < 2; ++mt)
        pa[mt] = *(const bf16x8*)&Pl[w][(mt * 16 + l15) * 72 + kk * 32 + quad * 8];
      __builtin_amdgcn_s_setprio(1);
#pragma unroll
      for (int mt = 0; mt < 2; ++mt)
        lacc[mt] = __builtin_amdgcn_mfma_f32_16x16x32_bf16(pa[mt], onesb, lacc[mt], 0, 0, 0);
#pragma unroll
      for (int nd = 0; nd < 4; ++nd) {
        bf16x8 vf = *(const bf16x8*)&Vtb[(nd * 16 + l15) * 64 + ((kk * 4 + quad) ^ swz) * 8];
#pragma unroll
        for (int mt = 0; mt < 2; ++mt)
          o[mt][nd] = __builtin_amdgcn_mfma_f32_16x16x32_bf16(pa[mt], vf, o[mt][nd], 0, 0, 0);
      }
      __builtin_amdgcn_s_setprio(0);
    }
  };

  // pipeline: tiles 0..15, tile t in buf t%3, prefetch distance 2.
  // per-wave stage = 4 gload_lds -> vmcnt(4): tile kb landed, tile kb+1 in flight.
  stage(0, 0);
  stage(64, 1);
  for (int kb = 0; kb < 15; ++kb) {
    asm volatile("s_waitcnt vmcnt(4)" ::: "memory");
    __builtin_amdgcn_s_barrier();
    if (kb < 14) stage((kb + 2) * 64, (kb + 2) % 3);  // overwrites buf (kb-1)%3: read done pre-barrier
    step(kb % 3);
  }
  asm volatile("s_waitcnt vmcnt(0)" ::: "memory");
  __builtin_amdgcn_s_barrier();
  step(0);                                             // tile 15 (15%3==0)

  // epilogue: out = mask[q] * O / l + query ; lacc[mt][r] = full row sum (all cols equal)
#pragma unroll
  for (int mt = 0; mt < 2; ++mt)
#pragma unroll
    for (int r = 0; r < 4; ++r) {
      const int rq = quad * 4 + r;
      const int row = q0w + mt * 16 + rq;
      const float scale = masks[b * 1024 + row] / lacc[mt][r];
#pragma unroll
      for (int nd = 0; nd < 4; ++nd) {
        const int col = h * 64 + nd * 16 + l15;
        const size_t gi = base + (size_t)row * 1024 + col;
        out[gi] = o[mt][nd][r] * scale + query[gi];
      }
    }
}

extern "C" void kernel_launch(void* const* d_in, const int* in_sizes, int n_in,
                              void* d_out, int out_size, void* d_ws, size_t ws_size,
                              hipStream_t stream) {
  const float* q     = (const float*)d_in[0];
  const float* k     = (const float*)d_in[1];
  const float* v     = (const float*)d_in[2];
  const float* masks = (const float*)d_in[3];
  const float* Wq    = (const float*)d_in[4];
  const float* bq    = (const float*)d_in[5];
  const float* Wk    = (const float*)d_in[6];
  const float* bk    = (const float*)d_in[7];
  const float* Wv    = (const float*)d_in[8];
  const float* bv    = (const float*)d_in[9];
  float* out = (float*)d_out;
  unsigned short* ws = (unsigned short*)d_ws;

  cvt_kernel<<<dim3(2048, 6), 256, 0, stream>>>(q, k, v, Wq, Wk, Wv, ws);
  proj_gemm<<<dim3(8, 32, 3), 256, 0, stream>>>(ws, bq, bk, bv);
  attn_kernel<<<dim3(64, 8), 256, 0, stream>>>(ws + QP_OFF, ws + KP_OFF, ws + VT_OFF,
                                               masks, q, out);
}